// Round 1
// baseline (470.873 us; speedup 1.0000x reference)
//
#include <hip/hip_runtime.h>
#include <math.h>

#define NB 2
#define NC 96
#define NN 8000
#define DI 192
#define DS 16
#define DTRK 6
#define KCH 125
#define LCH 64

// ws layout (element offsets, 4B each)
#define OFF_KEYS 0
#define OFF_RANK 8000
#define OFF_SIDX 16000
#define OFF_AEXP 24000
#define OFF_XC   32768                        // (B,N,DI) — reused as Y after scan
#define OFF_Z    (OFF_XC  + NB*NN*DI)
#define OFF_XCV  (OFF_Z   + NB*NN*DI)
#define OFF_DT   (OFF_XCV + NB*NN*DI)
#define OFF_BM   (OFF_DT  + NB*NN*DI)
#define OFF_CM   (OFF_BM  + NB*NN*DS)
#define OFF_CA   (OFF_CM  + NB*NN*DS)
#define OFF_CB   (OFF_CA  + NB*KCH*DI*DS)
#define OFF_HS   (OFF_CB  + NB*KCH*DI*DS)

// ---------------- A1: projection keys + A = -exp(A_log) ----------------
__global__ void k_keys(const float* __restrict__ pv, const float* __restrict__ alog,
                       float* __restrict__ keys, float* __restrict__ aexp) {
    int t = blockIdx.x * 256 + threadIdx.x;
    if (t < NN) {
        int z = t / 400, rem = t % 400, y = rem / 20, x = rem % 20;
        keys[t] = (float)z * pv[0] + (float)y * pv[1] + (float)x * pv[2];
    } else if (t < NN + DI * DS) {
        int i = t - NN;
        aexp[i] = -expf(alog[i]);
    }
}

// ---------------- A2: O(N^2) stable rank (tie-break on index) ----------------
__global__ void k_rank(const float* __restrict__ keys, int* __restrict__ rank) {
    __shared__ float kj[250];
    int t = threadIdx.x;
    int j0 = blockIdx.y * 250;
    if (t < 250) kj[t] = keys[j0 + t];
    __syncthreads();
    int i = blockIdx.x * 256 + t;
    if (i >= NN) return;
    float ki = keys[i];
    int cnt = 0;
    #pragma unroll 5
    for (int j = 0; j < 250; ++j) {
        float kv = kj[j];
        int jj = j0 + j;
        cnt += (kv < ki || (kv == ki && jj < i)) ? 1 : 0;
    }
    atomicAdd(rank + i, cnt);
}

// ---------------- A3: scatter sorted_idx[rank[i]] = i ----------------
__global__ void k_scatter(const int* __restrict__ rank, int* __restrict__ sidx) {
    int i = blockIdx.x * 256 + threadIdx.x;
    if (i < NN) sidx[rank[i]] = i;
}

// ---------------- B: gather + LayerNorm + in_proj (96 -> 384) ----------------
__launch_bounds__(256)
__global__ void k_ln_inproj(const float* __restrict__ x, const float* __restrict__ nw,
                            const float* __restrict__ nbp, const float* __restrict__ win,
                            const int* __restrict__ sidx,
                            float* __restrict__ xcout, float* __restrict__ zout) {
    __shared__ float xn[NC][36];
    int b = blockIdx.y;
    int n0 = blockIdx.x * 32;
    int t = threadIdx.x;
    int lane = t & 63, w = t >> 6;

    // LayerNorm: wave w handles positions w*8 .. w*8+7
    for (int q = 0; q < 8; ++q) {
        int p = w * 8 + q;
        int pidx = sidx[n0 + p];
        const float* xb = x + (size_t)b * NC * NN + pidx;
        float v1 = xb[(size_t)lane * NN];
        float v2 = (lane < 32) ? xb[(size_t)(lane + 64) * NN] : 0.f;
        float s = v1 + v2, sq = v1 * v1 + v2 * v2;
        #pragma unroll
        for (int m = 32; m >= 1; m >>= 1) { s += __shfl_xor(s, m); sq += __shfl_xor(sq, m); }
        float mu = s * (1.f / 96.f);
        float var = sq * (1.f / 96.f) - mu * mu;
        float rs = rsqrtf(var + 1e-5f);
        xn[lane][p] = (v1 - mu) * rs * nw[lane] + nbp[lane];
        if (lane < 32) xn[lane + 64][p] = (v2 - mu) * rs * nw[lane + 64] + nbp[lane + 64];
    }
    __syncthreads();

    // GEMM: 32 positions x 384 outputs; thread tile = 8 pos x 6 out
    int og = lane; // outputs og*6 .. og*6+5
    float acc[8][6] = {};
    for (int c = 0; c < 96; ++c) {
        float x8[8];
        *(float4*)&x8[0] = *(const float4*)&xn[c][w * 8];
        *(float4*)&x8[4] = *(const float4*)&xn[c][w * 8 + 4];
        #pragma unroll
        for (int j = 0; j < 6; ++j) {
            float wv = win[(og * 6 + j) * 96 + c];
            #pragma unroll
            for (int i = 0; i < 8; ++i) acc[i][j] = fmaf(x8[i], wv, acc[i][j]);
        }
    }
    int nbase = b * NN + n0 + w * 8;
    for (int i = 0; i < 8; ++i) {
        size_t row = (size_t)(nbase + i) * DI;
        #pragma unroll
        for (int j = 0; j < 6; ++j) {
            int o = og * 6 + j;
            if (o < DI) xcout[row + o] = acc[i][j];
            else        zout[row + o - DI] = acc[i][j];
        }
    }
}

// ---------------- D: depthwise causal conv + silu + x_proj + dt_proj ----------------
__launch_bounds__(256)
__global__ void k_conv_xproj(const float* __restrict__ cw, const float* __restrict__ cb,
                             const float* __restrict__ xpw, const float* __restrict__ dpw,
                             const float* __restrict__ dpb, const float* __restrict__ xcin,
                             float* __restrict__ xcvout, float* __restrict__ dtout,
                             float* __restrict__ bmout, float* __restrict__ cmout) {
    __shared__ float xcl[19][DI];
    __shared__ float xcv[16][196];
    __shared__ float dtr[16][DTRK];
    int b = blockIdx.y, n0 = blockIdx.x * 16, t = threadIdx.x;

    for (int idx = t; idx < 19 * DI; idx += 256) {
        int r = idx / DI, d = idx % DI;
        int n = n0 - 3 + r;
        xcl[r][d] = (n >= 0) ? xcin[((size_t)(b * NN + n)) * DI + d] : 0.f;
    }
    __syncthreads();

    for (int idx = t; idx < 16 * DI; idx += 256) {
        int p = idx / DI, d = idx % DI;
        float s = cb[d];
        #pragma unroll
        for (int k = 0; k < 4; ++k) s = fmaf(cw[d * 4 + k], xcl[p + k][d], s);
        s = s / (1.f + expf(-s));
        xcv[p][d] = s;
        xcvout[((size_t)(b * NN + n0 + p)) * DI + d] = s;
    }
    __syncthreads();

    for (int idx = t; idx < 16 * 38; idx += 256) {
        int p = idx / 38, e = idx % 38;
        const float4* wr = (const float4*)(xpw + e * DI);
        const float4* xr = (const float4*)&xcv[p][0];
        float acc = 0.f;
        #pragma unroll 8
        for (int dd = 0; dd < DI / 4; ++dd) {
            float4 wv = wr[dd]; float4 xv = xr[dd];
            acc += wv.x * xv.x + wv.y * xv.y + wv.z * xv.z + wv.w * xv.w;
        }
        int n = b * NN + n0 + p;
        if (e < DTRK) dtr[p][e] = acc;
        else if (e < DTRK + DS) bmout[(size_t)n * DS + (e - DTRK)] = acc;
        else                    cmout[(size_t)n * DS + (e - DTRK - DS)] = acc;
    }
    __syncthreads();

    for (int idx = t; idx < 16 * DI; idx += 256) {
        int p = idx / DI, d = idx % DI;
        float v = dpb[d];
        #pragma unroll
        for (int r = 0; r < DTRK; ++r) v = fmaf(dpw[d * DTRK + r], dtr[p][r], v);
        v = (v > 20.f) ? v : log1pf(expf(v));
        dtout[((size_t)(b * NN + n0 + p)) * DI + d] = v;
    }
}

// ---------------- E: scan phase 1 — per-chunk (prod A, local B) ----------------
__launch_bounds__(256)
__global__ void k_scan1(const float* __restrict__ aexp, const float* __restrict__ dt,
                        const float* __restrict__ xcv, const float* __restrict__ bm,
                        float* __restrict__ ca, float* __restrict__ cbv) {
    int t = threadIdx.x;
    int kc = blockIdx.x, dblk = blockIdx.y, b = blockIdx.z;
    int s = t & 15, dl = t >> 4;
    int d = dblk * 16 + dl;
    float a = aexp[d * DS + s];
    size_t ndbase = ((size_t)(b * NN + kc * LCH)) * DI + d;
    size_t nsbase = ((size_t)(b * NN + kc * LCH)) * DS + s;
    float ap = 1.f, bv = 0.f;
    #pragma unroll 4
    for (int i = 0; i < LCH; ++i) {
        float dtv = dt[ndbase + (size_t)i * DI];
        float xv  = xcv[ndbase + (size_t)i * DI];
        float bmv = bm[nsbase + (size_t)i * DS];
        float dA = __expf(dtv * a);
        ap *= dA;
        bv = fmaf(dA, bv, dtv * bmv * xv);
    }
    size_t cidx = ((size_t)(b * KCH + kc)) * (DI * DS) + dblk * 256 + t;
    ca[cidx] = ap;
    cbv[cidx] = bv;
}

// ---------------- F: scan phase 2 — sequential over chunks ----------------
__global__ void k_scan2(const float* __restrict__ ca, const float* __restrict__ cbv,
                        float* __restrict__ hs) {
    int tid = blockIdx.x * 256 + threadIdx.x; // 6144 total
    int b = tid / (DI * DS), dsx = tid % (DI * DS);
    float h = 0.f;
    for (int kc = 0; kc < KCH; ++kc) {
        size_t idx = ((size_t)(b * KCH + kc)) * (DI * DS) + dsx;
        hs[idx] = h;
        h = fmaf(ca[idx], h, cbv[idx]);
    }
}

// ---------------- G: scan phase 3 — replay + y + gate ----------------
__launch_bounds__(256)
__global__ void k_scan3(const float* __restrict__ aexp, const float* __restrict__ Dp,
                        const float* __restrict__ dt, const float* __restrict__ xcv,
                        const float* __restrict__ bm, const float* __restrict__ cm,
                        const float* __restrict__ zin, const float* __restrict__ hs,
                        float* __restrict__ yout) {
    int t = threadIdx.x;
    int kc = blockIdx.x, dblk = blockIdx.y, b = blockIdx.z;
    int s = t & 15, dl = t >> 4;
    int d = dblk * 16 + dl;
    float a = aexp[d * DS + s];
    float dpar = Dp[d];
    size_t ndbase = ((size_t)(b * NN + kc * LCH)) * DI + d;
    size_t nsbase = ((size_t)(b * NN + kc * LCH)) * DS + s;
    float h = hs[((size_t)(b * KCH + kc)) * (DI * DS) + dblk * 256 + t];
    for (int i = 0; i < LCH; ++i) {
        float dtv = dt[ndbase + (size_t)i * DI];
        float xv  = xcv[ndbase + (size_t)i * DI];
        float bmv = bm[nsbase + (size_t)i * DS];
        float cmv = cm[nsbase + (size_t)i * DS];
        float dA = __expf(dtv * a);
        h = fmaf(dA, h, dtv * bmv * xv);
        float r = h * cmv;
        r += __shfl_xor(r, 1);
        r += __shfl_xor(r, 2);
        r += __shfl_xor(r, 4);
        r += __shfl_xor(r, 8);
        if (s == 0) {
            float y = r + dpar * xv;
            float zv = zin[ndbase + (size_t)i * DI];
            y *= zv / (1.f + expf(-zv));
            yout[ndbase + (size_t)i * DI] = y;
        }
    }
}

// ---------------- H: out_proj (192 -> 96) + inverse-permute scatter ----------------
__launch_bounds__(256)
__global__ void k_outproj(const float* __restrict__ ow, const float* __restrict__ yin,
                          const int* __restrict__ sidx, float* __restrict__ out) {
    __shared__ float yl[DI][36];
    int b = blockIdx.y, n0 = blockIdx.x * 32, t = threadIdx.x;
    for (int li = t; li < 32 * 48; li += 256) {
        int p = li / 48, c4 = li % 48;
        float4 v = *(const float4*)&yin[((size_t)(b * NN + n0 + p)) * DI + c4 * 4];
        yl[c4 * 4 + 0][p] = v.x; yl[c4 * 4 + 1][p] = v.y;
        yl[c4 * 4 + 2][p] = v.z; yl[c4 * 4 + 3][p] = v.w;
    }
    __syncthreads();
    int w = t >> 6, og = t & 63;
    float acc0[8] = {}, acc1[8] = {};
    for (int d = 0; d < DI; ++d) {
        float y8[8];
        *(float4*)&y8[0] = *(const float4*)&yl[d][w * 8];
        *(float4*)&y8[4] = *(const float4*)&yl[d][w * 8 + 4];
        float w1 = ow[og * DI + d];
        float w2 = (og < 32) ? ow[(og + 64) * DI + d] : 0.f;
        #pragma unroll
        for (int i = 0; i < 8; ++i) {
            acc0[i] = fmaf(y8[i], w1, acc0[i]);
            acc1[i] = fmaf(y8[i], w2, acc1[i]);
        }
    }
    for (int q = 0; q < 8; ++q) {
        int n = n0 + w * 8 + q;
        int pidx = sidx[n];
        out[((size_t)(b * NC + og)) * NN + pidx] = acc0[q];
        if (og < 32) out[((size_t)(b * NC + og + 64)) * NN + pidx] = acc1[q];
    }
}

extern "C" void kernel_launch(void* const* d_in, const int* in_sizes, int n_in,
                              void* d_out, int out_size, void* d_ws, size_t ws_size,
                              hipStream_t stream) {
    const float* x    = (const float*)d_in[0];
    const float* pv   = (const float*)d_in[1];
    const float* nw   = (const float*)d_in[2];
    const float* nbp  = (const float*)d_in[3];
    const float* win  = (const float*)d_in[4];
    const float* cw   = (const float*)d_in[5];
    const float* cb   = (const float*)d_in[6];
    const float* xpw  = (const float*)d_in[7];
    const float* dpw  = (const float*)d_in[8];
    const float* dpb  = (const float*)d_in[9];
    const float* alog = (const float*)d_in[10];
    const float* Dp   = (const float*)d_in[11];
    const float* ow   = (const float*)d_in[12];
    float* out = (float*)d_out;
    float* ws  = (float*)d_ws;

    float* keys = ws + OFF_KEYS;
    int*   rank = (int*)ws + OFF_RANK;
    int*   sidx = (int*)ws + OFF_SIDX;
    float* aexp = ws + OFF_AEXP;
    float* xc   = ws + OFF_XC;
    float* z    = ws + OFF_Z;
    float* xcv  = ws + OFF_XCV;
    float* dt   = ws + OFF_DT;
    float* bmb  = ws + OFF_BM;
    float* cmb  = ws + OFF_CM;
    float* ca   = ws + OFF_CA;
    float* cbv  = ws + OFF_CB;
    float* hs   = ws + OFF_HS;
    float* y    = ws + OFF_XC;  // alias: xc dead after conv stage

    hipMemsetAsync(rank, 0, NN * sizeof(int), stream);
    k_keys<<<(NN + DI * DS + 255) / 256, 256, 0, stream>>>(pv, alog, keys, aexp);
    k_rank<<<dim3(32, 32), 256, 0, stream>>>(keys, rank);
    k_scatter<<<32, 256, 0, stream>>>(rank, sidx);
    k_ln_inproj<<<dim3(250, 2), 256, 0, stream>>>(x, nw, nbp, win, sidx, xc, z);
    k_conv_xproj<<<dim3(500, 2), 256, 0, stream>>>(cw, cb, xpw, dpw, dpb, xc, xcv, dt, bmb, cmb);
    k_scan1<<<dim3(KCH, 12, NB), 256, 0, stream>>>(aexp, dt, xcv, bmb, ca, cbv);
    k_scan2<<<24, 256, 0, stream>>>(ca, cbv, hs);
    k_scan3<<<dim3(KCH, 12, NB), 256, 0, stream>>>(aexp, Dp, dt, xcv, bmb, cmb, z, hs, y);
    k_outproj<<<dim3(250, 2), 256, 0, stream>>>(ow, y, sidx, out);
}

// Round 2
// 363.730 us; speedup vs baseline: 1.2946x; 1.2946x over previous
//
#include <hip/hip_runtime.h>
#include <math.h>

#define NB 2
#define NC 96
#define NN 8000
#define DI 192
#define DS 16
#define DTRK 6
#define KCH 125
#define LCH 64

// ws layout (element offsets, 4B each)
#define OFF_KEYS 0
#define OFF_RANK 8000
#define OFF_AEXP 24000
#define OFF_XC   32768                        // (B,N,DI) — reused as Y after scan
#define OFF_Z    (OFF_XC  + NB*NN*DI)
#define OFF_XCV  (OFF_Z   + NB*NN*DI)
#define OFF_DT   (OFF_XCV + NB*NN*DI)         // reused as YP (B,N,96) after scan3
#define OFF_BM   (OFF_DT  + NB*NN*DI)
#define OFF_CM   (OFF_BM  + NB*NN*DS)
#define OFF_CA   (OFF_CM  + NB*NN*DS)
#define OFF_CB   (OFF_CA  + NB*KCH*DI*DS)
#define OFF_HS   (OFF_CB  + NB*KCH*DI*DS)

// ---------------- A1: projection keys + A = -exp(A_log) ----------------
__global__ void k_keys(const float* __restrict__ pv, const float* __restrict__ alog,
                       float* __restrict__ keys, float* __restrict__ aexp) {
    int t = blockIdx.x * 256 + threadIdx.x;
    if (t < NN) {
        int z = t / 400, rem = t % 400, y = rem / 20, x = rem % 20;
        keys[t] = (float)z * pv[0] + (float)y * pv[1] + (float)x * pv[2];
    } else if (t < NN + DI * DS) {
        int i = t - NN;
        aexp[i] = -expf(alog[i]);
    }
}

// ---------------- A2: O(N^2) stable rank (tie-break on index) ----------------
__global__ void k_rank(const float* __restrict__ keys, int* __restrict__ rank) {
    __shared__ float kj[250];
    int t = threadIdx.x;
    int j0 = blockIdx.y * 250;
    if (t < 250) kj[t] = keys[j0 + t];
    __syncthreads();
    int i = blockIdx.x * 256 + t;
    if (i >= NN) return;
    float ki = keys[i];
    int cnt = 0;
    #pragma unroll 5
    for (int j = 0; j < 250; ++j) {
        float kv = kj[j];
        int jj = j0 + j;
        cnt += (kv < ki || (kv == ki && jj < i)) ? 1 : 0;
    }
    atomicAdd(rank + i, cnt);
}

// ------- B: coalesced read + LayerNorm + in_proj GEMM + row-scatter by rank -------
__launch_bounds__(256)
__global__ void k_ln_inproj(const float* __restrict__ x, const float* __restrict__ nw,
                            const float* __restrict__ nbp, const float* __restrict__ win,
                            const int* __restrict__ rank,
                            float* __restrict__ xcout, float* __restrict__ zout) {
    __shared__ float xt[32][97];     // [pos][chan], padded
    __shared__ float xnT[96][32];    // [chan][pos] normalized
    __shared__ float mu_s[32], rs_s[32];
    __shared__ int rk[32];
    int b = blockIdx.y, n0 = blockIdx.x * 32, t = threadIdx.x;
    if (t < 32) rk[t] = rank[n0 + t];
    // coalesced tile load: x[b][c][n0+p]
    for (int idx = t; idx < 96 * 32; idx += 256) {
        int c = idx >> 5, p = idx & 31;
        xt[p][c] = x[((size_t)b * NC + c) * NN + n0 + p];
    }
    __syncthreads();
    // LN stats: 8 threads per position, 12 channels each
    {
        int p = t >> 3, q = t & 7;
        float s = 0.f, sq = 0.f;
        #pragma unroll
        for (int j = 0; j < 12; ++j) { float v = xt[p][q * 12 + j]; s += v; sq += v * v; }
        s += __shfl_xor(s, 1); sq += __shfl_xor(sq, 1);
        s += __shfl_xor(s, 2); sq += __shfl_xor(sq, 2);
        s += __shfl_xor(s, 4); sq += __shfl_xor(sq, 4);
        if (q == 0) {
            float mu = s * (1.f / 96.f);
            float var = sq * (1.f / 96.f) - mu * mu;
            mu_s[p] = mu;
            rs_s[p] = rsqrtf(var + 1e-5f);
        }
    }
    __syncthreads();
    // normalize into transposed tile
    for (int idx = t; idx < 96 * 32; idx += 256) {
        int c = idx >> 5, p = idx & 31;
        xnT[c][p] = (xt[p][c] - mu_s[p]) * rs_s[p] * nw[c] + nbp[c];
    }
    __syncthreads();
    // GEMM: 32 pos x 384 out; thread = 8 pos x 6 out
    int og = t & 63, pg = t >> 6;
    float acc[8][6] = {};
    for (int c = 0; c < 96; ++c) {
        float x8[8];
        *(float4*)&x8[0] = *(const float4*)&xnT[c][pg * 8];
        *(float4*)&x8[4] = *(const float4*)&xnT[c][pg * 8 + 4];
        #pragma unroll
        for (int j = 0; j < 6; ++j) {
            float wv = win[(og * 6 + j) * NC + c];
            #pragma unroll
            for (int i = 0; i < 8; ++i) acc[i][j] = fmaf(x8[i], wv, acc[i][j]);
        }
    }
    // scatter whole rows to sorted position rank[n]
    for (int i = 0; i < 8; ++i) {
        int p = pg * 8 + i;
        size_t row = ((size_t)b * NN + rk[p]) * DI;
        #pragma unroll
        for (int j = 0; j < 6; ++j) {
            int o = og * 6 + j;
            if (o < DI) xcout[row + o] = acc[i][j];
            else        zout[row + o - DI] = acc[i][j];
        }
    }
}

// ---------------- D: depthwise causal conv + silu + x_proj + dt_proj ----------------
__launch_bounds__(256)
__global__ void k_conv_xproj(const float* __restrict__ cw, const float* __restrict__ cb,
                             const float* __restrict__ xpw, const float* __restrict__ dpw,
                             const float* __restrict__ dpb, const float* __restrict__ xcin,
                             float* __restrict__ xcvout, float* __restrict__ dtout,
                             float* __restrict__ bmout, float* __restrict__ cmout) {
    __shared__ float xcl[19][DI];
    __shared__ float xcv[16][196];
    __shared__ float dtr[16][DTRK];
    int b = blockIdx.y, n0 = blockIdx.x * 16, t = threadIdx.x;

    for (int idx = t; idx < 19 * DI; idx += 256) {
        int r = idx / DI, d = idx % DI;
        int n = n0 - 3 + r;
        xcl[r][d] = (n >= 0) ? xcin[((size_t)(b * NN + n)) * DI + d] : 0.f;
    }
    __syncthreads();

    for (int idx = t; idx < 16 * DI; idx += 256) {
        int p = idx / DI, d = idx % DI;
        float s = cb[d];
        #pragma unroll
        for (int k = 0; k < 4; ++k) s = fmaf(cw[d * 4 + k], xcl[p + k][d], s);
        s = s / (1.f + expf(-s));
        xcv[p][d] = s;
        xcvout[((size_t)(b * NN + n0 + p)) * DI + d] = s;
    }
    __syncthreads();

    for (int idx = t; idx < 16 * 38; idx += 256) {
        int p = idx / 38, e = idx % 38;
        const float4* wr = (const float4*)(xpw + e * DI);
        const float4* xr = (const float4*)&xcv[p][0];
        float acc = 0.f;
        #pragma unroll 8
        for (int dd = 0; dd < DI / 4; ++dd) {
            float4 wv = wr[dd]; float4 xv = xr[dd];
            acc += wv.x * xv.x + wv.y * xv.y + wv.z * xv.z + wv.w * xv.w;
        }
        int n = b * NN + n0 + p;
        if (e < DTRK) dtr[p][e] = acc;
        else if (e < DTRK + DS) bmout[(size_t)n * DS + (e - DTRK)] = acc;
        else                    cmout[(size_t)n * DS + (e - DTRK - DS)] = acc;
    }
    __syncthreads();

    for (int idx = t; idx < 16 * DI; idx += 256) {
        int p = idx / DI, d = idx % DI;
        float v = dpb[d];
        #pragma unroll
        for (int r = 0; r < DTRK; ++r) v = fmaf(dpw[d * DTRK + r], dtr[p][r], v);
        v = (v > 20.f) ? v : log1pf(expf(v));
        dtout[((size_t)(b * NN + n0 + p)) * DI + d] = v;
    }
}

// ---------------- E: scan phase 1 — per-chunk (prod A, local B), LDS-staged ----------------
__launch_bounds__(256)
__global__ void k_scan1(const float* __restrict__ aexp, const float* __restrict__ dt,
                        const float* __restrict__ xcv, const float* __restrict__ bm,
                        float* __restrict__ ca, float* __restrict__ cbv) {
    __shared__ float dt_t[64][16], xcv_t[64][16], bm_t[64][16];
    int t = threadIdx.x;
    int kc = blockIdx.x, dblk = blockIdx.y, b = blockIdx.z;
    size_t nbase = (size_t)b * NN + kc * LCH;
    for (int idx = t; idx < 1024; idx += 256) {
        int i = idx >> 4, v = idx & 15;
        dt_t[i][v]  = dt [(nbase + i) * DI + dblk * 16 + v];
        xcv_t[i][v] = xcv[(nbase + i) * DI + dblk * 16 + v];
        bm_t[i][v]  = bm [(nbase + i) * DS + v];
    }
    __syncthreads();
    int s = t & 15, dl = t >> 4;
    float a = aexp[(dblk * 16 + dl) * DS + s];
    float ap = 1.f, bv = 0.f;
    #pragma unroll 8
    for (int i = 0; i < LCH; ++i) {
        float dtv = dt_t[i][dl];
        float dA = __expf(dtv * a);
        ap *= dA;
        bv = fmaf(dA, bv, dtv * bm_t[i][s] * xcv_t[i][dl]);
    }
    size_t cidx = ((size_t)(b * KCH + kc)) * (DI * DS) + dblk * 256 + t;
    ca[cidx] = ap;
    cbv[cidx] = bv;
}

// ---------------- F: scan phase 2 — sequential over chunks ----------------
__global__ void k_scan2(const float* __restrict__ ca, const float* __restrict__ cbv,
                        float* __restrict__ hs) {
    int tid = blockIdx.x * 256 + threadIdx.x; // 6144 total
    int b = tid / (DI * DS), dsx = tid % (DI * DS);
    float h = 0.f;
    #pragma unroll 4
    for (int kc = 0; kc < KCH; ++kc) {
        size_t idx = ((size_t)(b * KCH + kc)) * (DI * DS) + dsx;
        hs[idx] = h;
        h = fmaf(ca[idx], h, cbv[idx]);
    }
}

// ---------------- G: scan phase 3 — replay + y + gate, LDS-staged ----------------
__launch_bounds__(256)
__global__ void k_scan3(const float* __restrict__ aexp, const float* __restrict__ Dp,
                        const float* __restrict__ dt, const float* __restrict__ xcv,
                        const float* __restrict__ bm, const float* __restrict__ cm,
                        const float* __restrict__ zin, const float* __restrict__ hs,
                        float* __restrict__ yout) {
    __shared__ float dt_t[64][16], xcv_t[64][16], bm_t[64][16], cm_t[64][16], z_t[64][16], y_t[64][16];
    int t = threadIdx.x;
    int kc = blockIdx.x, dblk = blockIdx.y, b = blockIdx.z;
    size_t nbase = (size_t)b * NN + kc * LCH;
    for (int idx = t; idx < 1024; idx += 256) {
        int i = idx >> 4, v = idx & 15;
        dt_t[i][v]  = dt [(nbase + i) * DI + dblk * 16 + v];
        xcv_t[i][v] = xcv[(nbase + i) * DI + dblk * 16 + v];
        z_t[i][v]   = zin[(nbase + i) * DI + dblk * 16 + v];
        bm_t[i][v]  = bm [(nbase + i) * DS + v];
        cm_t[i][v]  = cm [(nbase + i) * DS + v];
    }
    __syncthreads();
    int s = t & 15, dl = t >> 4;
    int d = dblk * 16 + dl;
    float a = aexp[d * DS + s];
    float dpar = Dp[d];
    float h = hs[((size_t)(b * KCH + kc)) * (DI * DS) + dblk * 256 + t];
    for (int i = 0; i < LCH; ++i) {
        float dtv = dt_t[i][dl];
        float xv  = xcv_t[i][dl];
        float dA = __expf(dtv * a);
        h = fmaf(dA, h, dtv * bm_t[i][s] * xv);
        float r = h * cm_t[i][s];
        r += __shfl_xor(r, 1);
        r += __shfl_xor(r, 2);
        r += __shfl_xor(r, 4);
        r += __shfl_xor(r, 8);
        if (s == 0) {
            float y = r + dpar * xv;
            float zv = z_t[i][dl];
            y *= zv / (1.f + expf(-zv));
            y_t[i][dl] = y;
        }
    }
    __syncthreads();
    for (int idx = t; idx < 1024; idx += 256) {
        int i = idx >> 4, v = idx & 15;
        yout[(nbase + i) * DI + dblk * 16 + v] = y_t[i][v];
    }
}

// ---------------- H: out_proj (192 -> 96), coalesced write in sorted order ----------------
__launch_bounds__(256)
__global__ void k_outproj(const float* __restrict__ ow, const float* __restrict__ yin,
                          float* __restrict__ yp) {
    __shared__ float yl[DI][36];
    int b = blockIdx.y, n0 = blockIdx.x * 32, t = threadIdx.x;
    for (int li = t; li < 32 * 48; li += 256) {
        int p = li / 48, c4 = li % 48;
        float4 v = *(const float4*)&yin[((size_t)(b * NN + n0 + p)) * DI + c4 * 4];
        yl[c4 * 4 + 0][p] = v.x; yl[c4 * 4 + 1][p] = v.y;
        yl[c4 * 4 + 2][p] = v.z; yl[c4 * 4 + 3][p] = v.w;
    }
    __syncthreads();
    int w = t >> 6, og = t & 63;
    float acc0[8] = {}, acc1[8] = {};
    for (int d = 0; d < DI; ++d) {
        float y8[8];
        *(float4*)&y8[0] = *(const float4*)&yl[d][w * 8];
        *(float4*)&y8[4] = *(const float4*)&yl[d][w * 8 + 4];
        float w1 = ow[og * DI + d];
        float w2 = (og < 32) ? ow[(og + 64) * DI + d] : 0.f;
        #pragma unroll
        for (int i = 0; i < 8; ++i) {
            acc0[i] = fmaf(y8[i], w1, acc0[i]);
            acc1[i] = fmaf(y8[i], w2, acc1[i]);
        }
    }
    for (int q = 0; q < 8; ++q) {
        int n = n0 + w * 8 + q;
        size_t row = ((size_t)b * NN + n) * NC;
        yp[row + og] = acc0[q];
        if (og < 32) yp[row + og + 64] = acc1[q];
    }
}

// ---------------- I: gather rows by rank + transpose + coalesced final write ----------------
__launch_bounds__(256)
__global__ void k_final(const float* __restrict__ yp, const int* __restrict__ rank,
                        float* __restrict__ out) {
    __shared__ float ft[64][97];
    __shared__ int rk[64];
    int b = blockIdx.y, i0 = blockIdx.x * 64, t = threadIdx.x;
    if (t < 64) rk[t] = rank[i0 + t];
    __syncthreads();
    for (int idx = t; idx < 64 * 24; idx += 256) {
        int ii = idx / 24, j = idx % 24;
        float4 v = *(const float4*)&yp[((size_t)b * NN + rk[ii]) * NC + j * 4];
        ft[ii][j * 4 + 0] = v.x; ft[ii][j * 4 + 1] = v.y;
        ft[ii][j * 4 + 2] = v.z; ft[ii][j * 4 + 3] = v.w;
    }
    __syncthreads();
    for (int idx = t; idx < 96 * 64; idx += 256) {
        int c = idx >> 6, ii = idx & 63;
        out[((size_t)b * NC + c) * NN + i0 + ii] = ft[ii][c];
    }
}

extern "C" void kernel_launch(void* const* d_in, const int* in_sizes, int n_in,
                              void* d_out, int out_size, void* d_ws, size_t ws_size,
                              hipStream_t stream) {
    const float* x    = (const float*)d_in[0];
    const float* pv   = (const float*)d_in[1];
    const float* nw   = (const float*)d_in[2];
    const float* nbp  = (const float*)d_in[3];
    const float* win  = (const float*)d_in[4];
    const float* cw   = (const float*)d_in[5];
    const float* cb   = (const float*)d_in[6];
    const float* xpw  = (const float*)d_in[7];
    const float* dpw  = (const float*)d_in[8];
    const float* dpb  = (const float*)d_in[9];
    const float* alog = (const float*)d_in[10];
    const float* Dp   = (const float*)d_in[11];
    const float* ow   = (const float*)d_in[12];
    float* out = (float*)d_out;
    float* ws  = (float*)d_ws;

    float* keys = ws + OFF_KEYS;
    int*   rank = (int*)ws + OFF_RANK;
    float* aexp = ws + OFF_AEXP;
    float* xc   = ws + OFF_XC;
    float* z    = ws + OFF_Z;
    float* xcv  = ws + OFF_XCV;
    float* dt   = ws + OFF_DT;
    float* bmb  = ws + OFF_BM;
    float* cmb  = ws + OFF_CM;
    float* ca   = ws + OFF_CA;
    float* cbv  = ws + OFF_CB;
    float* hs   = ws + OFF_HS;
    float* y    = ws + OFF_XC;  // alias: xc dead after conv stage
    float* yp   = ws + OFF_DT;  // alias: dt dead after scan3

    hipMemsetAsync(rank, 0, NN * sizeof(int), stream);
    k_keys<<<(NN + DI * DS + 255) / 256, 256, 0, stream>>>(pv, alog, keys, aexp);
    k_rank<<<dim3(32, 32), 256, 0, stream>>>(keys, rank);
    k_ln_inproj<<<dim3(250, 2), 256, 0, stream>>>(x, nw, nbp, win, rank, xc, z);
    k_conv_xproj<<<dim3(500, 2), 256, 0, stream>>>(cw, cb, xpw, dpw, dpb, xc, xcv, dt, bmb, cmb);
    k_scan1<<<dim3(KCH, 12, NB), 256, 0, stream>>>(aexp, dt, xcv, bmb, ca, cbv);
    k_scan2<<<24, 256, 0, stream>>>(ca, cbv, hs);
    k_scan3<<<dim3(KCH, 12, NB), 256, 0, stream>>>(aexp, Dp, dt, xcv, bmb, cmb, z, hs, y);
    k_outproj<<<dim3(250, 2), 256, 0, stream>>>(ow, y, yp);
    k_final<<<dim3(125, 2), 256, 0, stream>>>(yp, rank, out);
}

// Round 4
// 350.446 us; speedup vs baseline: 1.3436x; 1.0379x over previous
//
#include <hip/hip_runtime.h>
#include <math.h>

#define NB 2
#define NC 96
#define NN 8000
#define DI 192
#define DS 16
#define DTRK 6
#define KCH 125
#define LCH 64

// ws layout (element offsets, 4B each)
#define OFF_KEYS 0
#define OFF_RANK 8000
#define OFF_AEXP 24000
#define OFF_XC   32768                        // (B,N,DI) — reused as Y after scan
#define OFF_Z    (OFF_XC  + NB*NN*DI)
#define OFF_XCV  (OFF_Z   + NB*NN*DI)
#define OFF_DT   (OFF_XCV + NB*NN*DI)         // reused as YP (B,N,96) after scan3
#define OFF_BM   (OFF_DT  + NB*NN*DI)
#define OFF_CM   (OFF_BM  + NB*NN*DS)
#define OFF_CA   (OFF_CM  + NB*NN*DS)
#define OFF_CB   (OFF_CA  + NB*KCH*DI*DS)
#define OFF_HS   (OFF_CB  + NB*KCH*DI*DS)

// ---------------- A1: projection keys + A = -exp(A_log) ----------------
__global__ void k_keys(const float* __restrict__ pv, const float* __restrict__ alog,
                       float* __restrict__ keys, float* __restrict__ aexp) {
    int t = blockIdx.x * 256 + threadIdx.x;
    if (t < NN) {
        int z = t / 400, rem = t % 400, y = rem / 20, x = rem % 20;
        keys[t] = (float)z * pv[0] + (float)y * pv[1] + (float)x * pv[2];
    } else if (t < NN + DI * DS) {
        int i = t - NN;
        aexp[i] = -expf(alog[i]);
    }
}

// ---------------- A2: O(N^2) stable rank (tie-break on index) ----------------
__global__ void k_rank(const float* __restrict__ keys, int* __restrict__ rank) {
    __shared__ float kj[250];
    int t = threadIdx.x;
    int j0 = blockIdx.y * 250;
    if (t < 250) kj[t] = keys[j0 + t];
    __syncthreads();
    int i = blockIdx.x * 256 + t;
    if (i >= NN) return;
    float ki = keys[i];
    int cnt = 0;
    #pragma unroll 5
    for (int j = 0; j < 250; ++j) {
        float kv = kj[j];
        int jj = j0 + j;
        cnt += (kv < ki || (kv == ki && jj < i)) ? 1 : 0;
    }
    atomicAdd(rank + i, cnt);
}

// ------- B: LN + in_proj, lane=position, wave-uniform W, two staged passes -------
__launch_bounds__(256)
__global__ void k_ln_inproj(const float* __restrict__ x, const float* __restrict__ nw,
                            const float* __restrict__ nbp, const float* __restrict__ win,
                            const int* __restrict__ rank,
                            float* __restrict__ xcout, float* __restrict__ zout) {
    __shared__ float smem[64 * 197];          // union: xt[64][97] then st[64][197]
    __shared__ int rk[64];
    __shared__ float nwb[NC], nbb[NC];
    float (*xt)[97]  = (float(*)[97])smem;
    float (*st)[197] = (float(*)[197])smem;

    int b = blockIdx.y, n0 = blockIdx.x * 64, t = threadIdx.x;
    int lane = t & 63, w = t >> 6;
    if (t < 64) rk[t] = rank[n0 + t];
    if (t >= 64 && t < 160) { int c = t - 64; nwb[c] = nw[c]; nbb[c] = nbp[c]; }
    // coalesced tile load: x[b][c][n0+p] -> xt[p][c]
    for (int idx = t; idx < NC * 64; idx += 256) {
        int c = idx >> 6, p = idx & 63;
        xt[p][c] = x[((size_t)b * NC + c) * NN + n0 + p];
    }
    __syncthreads();

    // per-lane LN into registers (each wave redundant for its own lane=pos)
    float xr[96];
    float s = 0.f, sq = 0.f;
    #pragma unroll
    for (int c4 = 0; c4 < 24; ++c4) {
        float4 v = *(const float4*)&xt[lane][c4 * 4];
        xr[c4*4+0] = v.x; xr[c4*4+1] = v.y; xr[c4*4+2] = v.z; xr[c4*4+3] = v.w;
        s += v.x + v.y + v.z + v.w;
        sq += v.x*v.x + v.y*v.y + v.z*v.z + v.w*v.w;
    }
    float mu = s * (1.f / 96.f);
    float var = sq * (1.f / 96.f) - mu * mu;
    float rs = rsqrtf(var + 1e-5f);
    #pragma unroll
    for (int c = 0; c < 96; ++c) xr[c] = (xr[c] - mu) * rs * nwb[c] + nbb[c];
    __syncthreads();   // xt dead, reuse as st

    // two passes: pass 0 -> xc (win rows 0..191), pass 1 -> z (rows 192..383)
    for (int pass = 0; pass < 2; ++pass) {
        const float* wbase = win + ((size_t)pass * DI + w * 48) * NC;
        for (int oi = 0; oi < 48; oi += 2) {
            const float4* wp0 = (const float4*)(wbase + (size_t)oi * NC);
            const float4* wp1 = (const float4*)(wbase + (size_t)(oi + 1) * NC);
            float a0 = 0.f, b0 = 0.f, a1 = 0.f, b1 = 0.f;
            #pragma unroll
            for (int c4 = 0; c4 < 24; c4 += 2) {
                float4 u0 = wp0[c4], u1 = wp1[c4];
                a0 = fmaf(xr[4*c4+0], u0.x, fmaf(xr[4*c4+1], u0.y, fmaf(xr[4*c4+2], u0.z, fmaf(xr[4*c4+3], u0.w, a0))));
                a1 = fmaf(xr[4*c4+0], u1.x, fmaf(xr[4*c4+1], u1.y, fmaf(xr[4*c4+2], u1.z, fmaf(xr[4*c4+3], u1.w, a1))));
                float4 v0 = wp0[c4+1], v1 = wp1[c4+1];
                b0 = fmaf(xr[4*c4+4], v0.x, fmaf(xr[4*c4+5], v0.y, fmaf(xr[4*c4+6], v0.z, fmaf(xr[4*c4+7], v0.w, b0))));
                b1 = fmaf(xr[4*c4+4], v1.x, fmaf(xr[4*c4+5], v1.y, fmaf(xr[4*c4+6], v1.z, fmaf(xr[4*c4+7], v1.w, b1))));
            }
            st[lane][w * 48 + oi]     = a0 + b0;
            st[lane][w * 48 + oi + 1] = a1 + b1;
        }
        __syncthreads();
        float* outp = (pass == 0) ? xcout : zout;
        for (int idx = t; idx < 64 * 48; idx += 256) {
            int p = idx / 48, o4 = idx % 48;
            size_t row = ((size_t)b * NN + rk[p]) * DI;
            *(float4*)&outp[row + o4 * 4] = *(const float4*)&st[p][o4 * 4];
        }
        __syncthreads();   // before next pass overwrites st
    }
}

// ------- D: conv+silu + x_proj + dt_proj, wave-uniform W -------
__launch_bounds__(256)
__global__ void k_conv_xproj(const float* __restrict__ cw, const float* __restrict__ cb,
                             const float* __restrict__ xpw, const float* __restrict__ dpw,
                             const float* __restrict__ dpb, const float* __restrict__ xcin,
                             float* __restrict__ xcvout, float* __restrict__ dtout,
                             float* __restrict__ bmout, float* __restrict__ cmout) {
    __shared__ float xcv[64][193];      // reused as dts after x_proj
    __shared__ float dtrT[DTRK][64];
    __shared__ float bc[64][33];
    __shared__ float cwl[4][DI];
    __shared__ float cbl[DI];
    int b = blockIdx.y, n0 = blockIdx.x * 64, t = threadIdx.x;
    int lane = t & 63, w = t >> 6;

    if (t < DI) {
        cbl[t] = cb[t];
        #pragma unroll
        for (int k = 0; k < 4; ++k) cwl[k][t] = cw[t * 4 + k];
    }
    __syncthreads();

    // conv + silu: direct global reads (coalesced), store LDS + global
    for (int idx = t; idx < 64 * DI; idx += 256) {
        int p = idx / DI, d = idx % DI;
        float s = cbl[d];
        #pragma unroll
        for (int k = 0; k < 4; ++k) {
            int n = n0 + p - 3 + k;
            float xv = (n >= 0) ? xcin[((size_t)b * NN + n) * DI + d] : 0.f;
            s = fmaf(cwl[k][d], xv, s);
        }
        s = s / (1.f + expf(-s));
        xcv[p][d] = s;
        xcvout[((size_t)(b * NN + n0 + p)) * DI + d] = s;
    }
    __syncthreads();

    // x_proj: lane = position, wave w -> outputs e = w, w+4, ...
    {
        float acc[10] = {};
        for (int c4 = 0; c4 < 48; ++c4) {
            float4 xv = *(const float4*)&xcv[lane][c4 * 4];
            #pragma unroll
            for (int j = 0; j < 10; ++j) {
                int e = w + 4 * j;
                if (e < 38) {
                    float4 w4 = *(const float4*)&xpw[(size_t)e * DI + c4 * 4];
                    acc[j] = fmaf(xv.x, w4.x, fmaf(xv.y, w4.y, fmaf(xv.z, w4.z, fmaf(xv.w, w4.w, acc[j]))));
                }
            }
        }
        #pragma unroll
        for (int j = 0; j < 10; ++j) {
            int e = w + 4 * j;
            if (e < 38) {
                if (e < DTRK) dtrT[e][lane] = acc[j];
                else          bc[lane][e - DTRK] = acc[j];
            }
        }
    }
    __syncthreads();

    // write Bm/Cm coalesced
    for (int idx = t; idx < 64 * DS; idx += 256) {
        int p = idx / DS, sidx = idx % DS;
        int n = b * NN + n0 + p;
        bmout[(size_t)n * DS + sidx] = bc[p][sidx];
        cmout[(size_t)n * DS + sidx] = bc[p][DS + sidx];
    }

    // dt_proj + softplus: lane = position, wave w -> d in [w*48, w*48+48)
    float dts_loc[48];
    {
        int d0 = w * 48;
        #pragma unroll 8
        for (int jd = 0; jd < 48; ++jd) {
            int d = d0 + jd;
            float v = dpb[d];
            #pragma unroll
            for (int r = 0; r < DTRK; ++r) v = fmaf(dpw[d * DTRK + r], dtrT[r][lane], v);
            v = (v > 20.f) ? v : log1pf(expf(v));
            dts_loc[jd] = v;
        }
    }
    __syncthreads();   // everyone done reading xcv
    {
        int d0 = w * 48;
        #pragma unroll 8
        for (int jd = 0; jd < 48; ++jd) xcv[lane][d0 + jd] = dts_loc[jd];
    }
    __syncthreads();
    for (int idx = t; idx < 64 * DI; idx += 256) {
        int p = idx / DI, d = idx % DI;
        dtout[((size_t)(b * NN + n0 + p)) * DI + d] = xcv[p][d];
    }
}

// ---------------- E: scan phase 1 — per-chunk (prod A, local B), LDS-staged ----------------
__launch_bounds__(256)
__global__ void k_scan1(const float* __restrict__ aexp, const float* __restrict__ dt,
                        const float* __restrict__ xcv, const float* __restrict__ bm,
                        float* __restrict__ ca, float* __restrict__ cbv) {
    __shared__ float dt_t[64][16], xcv_t[64][16], bm_t[64][16];
    int t = threadIdx.x;
    int kc = blockIdx.x, dblk = blockIdx.y, b = blockIdx.z;
    size_t nbase = (size_t)b * NN + kc * LCH;
    for (int idx = t; idx < 1024; idx += 256) {
        int i = idx >> 4, v = idx & 15;
        dt_t[i][v]  = dt [(nbase + i) * DI + dblk * 16 + v];
        xcv_t[i][v] = xcv[(nbase + i) * DI + dblk * 16 + v];
        bm_t[i][v]  = bm [(nbase + i) * DS + v];
    }
    __syncthreads();
    int s = t & 15, dl = t >> 4;
    float a = aexp[(dblk * 16 + dl) * DS + s];
    float ap = 1.f, bv = 0.f;
    #pragma unroll 8
    for (int i = 0; i < LCH; ++i) {
        float dtv = dt_t[i][dl];
        float dA = __expf(dtv * a);
        ap *= dA;
        bv = fmaf(dA, bv, dtv * bm_t[i][s] * xcv_t[i][dl]);
    }
    size_t cidx = ((size_t)(b * KCH + kc)) * (DI * DS) + dblk * 256 + t;
    ca[cidx] = ap;
    cbv[cidx] = bv;
}

// ---------------- F: scan phase 2 — sequential over chunks ----------------
__global__ void k_scan2(const float* __restrict__ ca, const float* __restrict__ cbv,
                        float* __restrict__ hs) {
    int tid = blockIdx.x * 64 + threadIdx.x; // 6144 total
    int b = tid / (DI * DS), dsx = tid % (DI * DS);
    float h = 0.f;
    size_t base = (size_t)b * KCH * (DI * DS) + dsx;
    #pragma unroll 5
    for (int kc = 0; kc < KCH; ++kc) {
        size_t idx = base + (size_t)kc * (DI * DS);
        hs[idx] = h;
        h = fmaf(ca[idx], h, cbv[idx]);
    }
}

// ---------------- G: scan phase 3 — replay + y + gate, LDS-staged ----------------
__launch_bounds__(256)
__global__ void k_scan3(const float* __restrict__ aexp, const float* __restrict__ Dp,
                        const float* __restrict__ dt, const float* __restrict__ xcv,
                        const float* __restrict__ bm, const float* __restrict__ cm,
                        const float* __restrict__ zin, const float* __restrict__ hs,
                        float* __restrict__ yout) {
    __shared__ float dt_t[64][16], xcv_t[64][16], bm_t[64][16], cm_t[64][16], z_t[64][16], y_t[64][16];
    int t = threadIdx.x;
    int kc = blockIdx.x, dblk = blockIdx.y, b = blockIdx.z;
    size_t nbase = (size_t)b * NN + kc * LCH;
    for (int idx = t; idx < 1024; idx += 256) {
        int i = idx >> 4, v = idx & 15;
        dt_t[i][v]  = dt [(nbase + i) * DI + dblk * 16 + v];
        xcv_t[i][v] = xcv[(nbase + i) * DI + dblk * 16 + v];
        z_t[i][v]   = zin[(nbase + i) * DI + dblk * 16 + v];
        bm_t[i][v]  = bm [(nbase + i) * DS + v];
        cm_t[i][v]  = cm [(nbase + i) * DS + v];
    }
    __syncthreads();
    int s = t & 15, dl = t >> 4;
    int d = dblk * 16 + dl;
    float a = aexp[d * DS + s];
    float dpar = Dp[d];
    float h = hs[((size_t)(b * KCH + kc)) * (DI * DS) + dblk * 256 + t];
    for (int i = 0; i < LCH; ++i) {
        float dtv = dt_t[i][dl];
        float xv  = xcv_t[i][dl];
        float dA = __expf(dtv * a);
        h = fmaf(dA, h, dtv * bm_t[i][s] * xv);
        float r = h * cm_t[i][s];
        r += __shfl_xor(r, 1);
        r += __shfl_xor(r, 2);
        r += __shfl_xor(r, 4);
        r += __shfl_xor(r, 8);
        if (s == 0) {
            float y = r + dpar * xv;
            float zv = z_t[i][dl];
            y *= zv / (1.f + expf(-zv));
            y_t[i][dl] = y;
        }
    }
    __syncthreads();
    for (int idx = t; idx < 1024; idx += 256) {
        int i = idx >> 4, v = idx & 15;
        yout[(nbase + i) * DI + dblk * 16 + v] = y_t[i][v];
    }
}

// ------- H: out_proj (192 -> 96), wave-uniform W, coalesced staged write -------
__launch_bounds__(256)
__global__ void k_outproj(const float* __restrict__ ow, const float* __restrict__ yin,
                          float* __restrict__ yp) {
    __shared__ float yt[32][193];
    __shared__ float yo[32][97];
    int b = blockIdx.y, n0 = blockIdx.x * 32, t = threadIdx.x;
    int lane = t & 63, w = t >> 6;
    int h = lane >> 5, p = lane & 31;
    for (int idx = t; idx < 32 * DI; idx += 256) {
        int pp = idx / DI, d = idx % DI;
        yt[pp][d] = yin[((size_t)(b * NN + n0 + pp)) * DI + d];
    }
    __syncthreads();
    float acc[12] = {};
    for (int c4 = 0; c4 < 48; ++c4) {
        float4 yv = *(const float4*)&yt[p][c4 * 4];
        #pragma unroll
        for (int j = 0; j < 12; ++j) {
            int og = w + 4 * (2 * j + h);
            float4 w4 = *(const float4*)&ow[(size_t)og * DI + c4 * 4];
            acc[j] = fmaf(yv.x, w4.x, fmaf(yv.y, w4.y, fmaf(yv.z, w4.z, fmaf(yv.w, w4.w, acc[j]))));
        }
    }
    #pragma unroll
    for (int j = 0; j < 12; ++j) yo[p][w + 4 * (2 * j + h)] = acc[j];
    __syncthreads();
    for (int idx = t; idx < 32 * 24; idx += 256) {
        int pp = idx / 24, o4 = idx % 24;
        *(float4*)&yp[((size_t)b * NN + n0 + pp) * NC + o4 * 4] = *(const float4*)&yo[pp][o4 * 4];
    }
}

// ---------------- I: gather rows by rank + transpose + coalesced final write ----------------
__launch_bounds__(256)
__global__ void k_final(const float* __restrict__ yp, const int* __restrict__ rank,
                        float* __restrict__ out) {
    __shared__ float ft[64][97];
    __shared__ int rk[64];
    int b = blockIdx.y, i0 = blockIdx.x * 64, t = threadIdx.x;
    if (t < 64) rk[t] = rank[i0 + t];
    __syncthreads();
    for (int idx = t; idx < 64 * 24; idx += 256) {
        int ii = idx / 24, j = idx % 24;
        float4 v = *(const float4*)&yp[((size_t)b * NN + rk[ii]) * NC + j * 4];
        ft[ii][j * 4 + 0] = v.x; ft[ii][j * 4 + 1] = v.y;
        ft[ii][j * 4 + 2] = v.z; ft[ii][j * 4 + 3] = v.w;
    }
    __syncthreads();
    for (int idx = t; idx < 96 * 64; idx += 256) {
        int c = idx >> 6, ii = idx & 63;
        out[((size_t)b * NC + c) * NN + i0 + ii] = ft[ii][c];
    }
}

extern "C" void kernel_launch(void* const* d_in, const int* in_sizes, int n_in,
                              void* d_out, int out_size, void* d_ws, size_t ws_size,
                              hipStream_t stream) {
    const float* x    = (const float*)d_in[0];
    const float* pv   = (const float*)d_in[1];
    const float* nw   = (const float*)d_in[2];
    const float* nbp  = (const float*)d_in[3];
    const float* win  = (const float*)d_in[4];
    const float* cw   = (const float*)d_in[5];
    const float* cb   = (const float*)d_in[6];
    const float* xpw  = (const float*)d_in[7];
    const float* dpw  = (const float*)d_in[8];
    const float* dpb  = (const float*)d_in[9];
    const float* alog = (const float*)d_in[10];
    const float* Dp   = (const float*)d_in[11];
    const float* ow   = (const float*)d_in[12];
    float* out = (float*)d_out;
    float* ws  = (float*)d_ws;

    float* keys = ws + OFF_KEYS;
    int*   rank = (int*)ws + OFF_RANK;
    float* aexp = ws + OFF_AEXP;
    float* xc   = ws + OFF_XC;
    float* z    = ws + OFF_Z;
    float* xcv  = ws + OFF_XCV;
    float* dt   = ws + OFF_DT;
    float* bmb  = ws + OFF_BM;
    float* cmb  = ws + OFF_CM;
    float* ca   = ws + OFF_CA;
    float* cbv  = ws + OFF_CB;
    float* hs   = ws + OFF_HS;
    float* y    = ws + OFF_XC;  // alias: xc dead after conv stage
    float* yp   = ws + OFF_DT;  // alias: dt dead after scan3

    hipMemsetAsync(rank, 0, NN * sizeof(int), stream);
    k_keys<<<(NN + DI * DS + 255) / 256, 256, 0, stream>>>(pv, alog, keys, aexp);
    k_rank<<<dim3(32, 32), 256, 0, stream>>>(keys, rank);
    k_ln_inproj<<<dim3(125, 2), 256, 0, stream>>>(x, nw, nbp, win, rank, xc, z);
    k_conv_xproj<<<dim3(125, 2), 256, 0, stream>>>(cw, cb, xpw, dpw, dpb, xc, xcv, dt, bmb, cmb);
    k_scan1<<<dim3(KCH, 12, NB), 256, 0, stream>>>(aexp, dt, xcv, bmb, ca, cbv);
    k_scan2<<<96, 64, 0, stream>>>(ca, cbv, hs);
    k_scan3<<<dim3(KCH, 12, NB), 256, 0, stream>>>(aexp, Dp, dt, xcv, bmb, cmb, z, hs, y);
    k_outproj<<<dim3(250, 2), 256, 0, stream>>>(ow, y, yp);
    k_final<<<dim3(125, 2), 256, 0, stream>>>(yp, rank, out);
}

// Round 5
// 291.794 us; speedup vs baseline: 1.6137x; 1.2010x over previous
//
#include <hip/hip_runtime.h>
#include <math.h>

#define NB 2
#define NC 96
#define NN 8000
#define DI 192
#define DS 16
#define DTRK 6
#define KCH 125
#define LCH 64

// ws layout (element offsets, 4B each)
#define OFF_KEYS 0
#define OFF_RANK 8000
#define OFF_AEXP 24000
#define OFF_XC   32768                        // (B,N,DI) — reused as Y after scan
#define OFF_Z    (OFF_XC  + NB*NN*DI)
#define OFF_XCV  (OFF_Z   + NB*NN*DI)
#define OFF_DT   (OFF_XCV + NB*NN*DI)         // reused as YP (B,N,96) after scan3
#define OFF_BM   (OFF_DT  + NB*NN*DI)
#define OFF_CM   (OFF_BM  + NB*NN*DS)
#define OFF_CA   (OFF_CM  + NB*NN*DS)         // xn (B,N,96) aliases ca+cb (pre-scan)
#define OFF_CB   (OFF_CA  + NB*KCH*DI*DS)
#define OFF_HS   (OFF_CB  + NB*KCH*DI*DS)

// ---------------- A1: projection keys + A = -exp(A_log) ----------------
__global__ void k_keys(const float* __restrict__ pv, const float* __restrict__ alog,
                       float* __restrict__ keys, float* __restrict__ aexp) {
    int t = blockIdx.x * 256 + threadIdx.x;
    if (t < NN) {
        int z = t / 400, rem = t % 400, y = rem / 20, x = rem % 20;
        keys[t] = (float)z * pv[0] + (float)y * pv[1] + (float)x * pv[2];
    } else if (t < NN + DI * DS) {
        int i = t - NN;
        aexp[i] = -expf(alog[i]);
    }
}

// ---------------- A2: O(N^2) stable rank (tie-break on index) ----------------
__global__ void k_rank(const float* __restrict__ keys, int* __restrict__ rank) {
    __shared__ float kj[250];
    int t = threadIdx.x;
    int j0 = blockIdx.y * 250;
    if (t < 250) kj[t] = keys[j0 + t];
    __syncthreads();
    int i = blockIdx.x * 256 + t;
    if (i >= NN) return;
    float ki = keys[i];
    int cnt = 0;
    #pragma unroll 5
    for (int j = 0; j < 250; ++j) {
        float kv = kj[j];
        int jj = j0 + j;
        cnt += (kv < ki || (kv == ki && jj < i)) ? 1 : 0;
    }
    atomicAdd(rank + i, cnt);
}

// ------- B1: LayerNorm + row-scatter to sorted xn (B,N,96) -------
__launch_bounds__(256)
__global__ void k_ln(const float* __restrict__ x, const float* __restrict__ nw,
                     const float* __restrict__ nbp, const int* __restrict__ rank,
                     float* __restrict__ xn) {
    __shared__ float xt[64][100];
    __shared__ int rk[64];
    __shared__ float nwb[NC], nbb[NC];
    int b = blockIdx.y, n0 = blockIdx.x * 64, t = threadIdx.x;
    int lane = t & 63, w = t >> 6;
    if (t < 64) rk[t] = rank[n0 + t];
    else if (t < 160) { int c = t - 64; nwb[c] = nw[c]; nbb[c] = nbp[c]; }
    for (int idx = t; idx < NC * 64; idx += 256) {
        int c = idx >> 6, p = idx & 63;
        xt[p][c] = x[((size_t)b * NC + c) * NN + n0 + p];
    }
    __syncthreads();
    // per-lane LN (4 waves redundant)
    float xr[96];
    float s = 0.f, sq = 0.f;
    #pragma unroll
    for (int c4 = 0; c4 < 24; ++c4) {
        float4 v = *(const float4*)&xt[lane][c4 * 4];
        xr[c4*4+0] = v.x; xr[c4*4+1] = v.y; xr[c4*4+2] = v.z; xr[c4*4+3] = v.w;
        s += v.x + v.y + v.z + v.w;
        sq += v.x*v.x + v.y*v.y + v.z*v.z + v.w*v.w;
    }
    float mu = s * (1.f / 96.f);
    float var = sq * (1.f / 96.f) - mu * mu;
    float rs = rsqrtf(var + 1e-5f);
    #pragma unroll
    for (int c = 0; c < 96; ++c) xr[c] = (xr[c] - mu) * rs * nwb[c] + nbb[c];
    __syncthreads();
    if (w == 0) {
        #pragma unroll
        for (int c = 0; c < 96; ++c) xt[lane][c] = xr[c];
    }
    __syncthreads();
    for (int idx = t; idx < 64 * 24; idx += 256) {
        int p = idx / 24, c4 = idx % 24;
        *(float4*)&xn[((size_t)b * NN + rk[p]) * NC + c4 * 4] = *(const float4*)&xt[p][c4 * 4];
    }
}

// ------- B2: in_proj GEMM (16000 x 384 x 96), 4 output groups, high occupancy -------
__launch_bounds__(256, 4)
__global__ void k_inproj(const float* __restrict__ xn, const float* __restrict__ win,
                         float* __restrict__ xcout, float* __restrict__ zout) {
    __shared__ float smem[6400];               // union: xs[96][65] then st[64][100]
    float (*xs)[65]  = (float(*)[65])smem;
    float (*st)[100] = (float(*)[100])smem;
    int b = blockIdx.z, g = blockIdx.y, n0 = blockIdx.x * 64, t = threadIdx.x;
    int lane = t & 63, w = t >> 6;
    for (int idx = t; idx < 64 * 96; idx += 256) {
        int p = idx / 96, c = idx % 96;
        xs[c][p] = xn[((size_t)b * NN + n0 + p) * NC + c];
    }
    __syncthreads();
    const float* wb = win + (size_t)(g * 96 + w * 24) * NC;
    float acc[24];
    #pragma unroll
    for (int j = 0; j < 24; ++j) acc[j] = 0.f;
    for (int c4 = 0; c4 < 24; ++c4) {
        float x0 = xs[c4*4+0][lane], x1 = xs[c4*4+1][lane];
        float x2 = xs[c4*4+2][lane], x3 = xs[c4*4+3][lane];
        #pragma unroll
        for (int j = 0; j < 24; ++j) {
            float4 w4 = *(const float4*)(wb + (size_t)j * NC + c4 * 4);
            acc[j] = fmaf(x0, w4.x, fmaf(x1, w4.y, fmaf(x2, w4.z, fmaf(x3, w4.w, acc[j]))));
        }
    }
    __syncthreads();   // xs dead
    #pragma unroll
    for (int j = 0; j < 24; ++j) st[lane][w * 24 + j] = acc[j];
    __syncthreads();
    float* outp = (g < 2) ? xcout : zout;
    int co = (g & 1) * 96;
    for (int idx = t; idx < 64 * 24; idx += 256) {
        int p = idx / 24, o4 = idx % 24;
        *(float4*)&outp[((size_t)b * NN + n0 + p) * DI + co + o4 * 4] = *(const float4*)&st[p][o4 * 4];
    }
}

// ------- D: conv+silu + x_proj + dt_proj, 16-pos tiles, 4-way K-split -------
__launch_bounds__(256, 4)
__global__ void k_conv_xdt(const float* __restrict__ cw, const float* __restrict__ cb,
                           const float* __restrict__ xpw, const float* __restrict__ dpw,
                           const float* __restrict__ dpb, const float* __restrict__ xcin,
                           float* __restrict__ xcvout, float* __restrict__ dtout,
                           float* __restrict__ bmout, float* __restrict__ cmout) {
    __shared__ float xcv[16][196];             // reused as dt stage at the end
    __shared__ float dtrT[DTRK][16];
    __shared__ float bc[16][33];
    int b = blockIdx.y, n0 = blockIdx.x * 16, t = threadIdx.x;
    int lane = t & 63, w = t >> 6;
    int p = lane & 15, q = lane >> 4;

    // conv + silu
    for (int idx = t; idx < 16 * DI; idx += 256) {
        int pp = idx / DI, d = idx % DI;
        float s = cb[d];
        #pragma unroll
        for (int k = 0; k < 4; ++k) {
            int n = n0 + pp - 3 + k;
            float xv = (n >= 0) ? xcin[((size_t)b * NN + n) * DI + d] : 0.f;
            s = fmaf(cw[d * 4 + k], xv, s);
        }
        s = s / (1.f + expf(-s));
        xcv[pp][d] = s;
        xcvout[((size_t)b * NN + n0 + pp) * DI + d] = s;
    }
    __syncthreads();

    // x_proj: lane=(p,q); q = K-quarter; wave w -> outputs e = w+4j
    float acc[10];
    #pragma unroll
    for (int j = 0; j < 10; ++j) acc[j] = 0.f;
    for (int ci = 0; ci < 12; ++ci) {
        int c4 = q * 12 + ci;
        float4 xv = *(const float4*)&xcv[p][c4 * 4];
        #pragma unroll
        for (int j = 0; j < 10; ++j) {
            int e = w + 4 * j;
            if (e < 38) {
                float4 w4 = *(const float4*)&xpw[(size_t)e * DI + c4 * 4];
                acc[j] = fmaf(xv.x, w4.x, fmaf(xv.y, w4.y, fmaf(xv.z, w4.z, fmaf(xv.w, w4.w, acc[j]))));
            }
        }
    }
    #pragma unroll
    for (int j = 0; j < 10; ++j) {
        acc[j] += __shfl_xor(acc[j], 16);
        acc[j] += __shfl_xor(acc[j], 32);
    }
    if (lane < 16) {
        #pragma unroll
        for (int j = 0; j < 10; ++j) {
            int e = w + 4 * j;
            if (e < DTRK) dtrT[e][p] = acc[j];
            else if (e < 38) bc[p][e - DTRK] = acc[j];
        }
    }
    __syncthreads();

    // Bm/Cm coalesced
    for (int idx = t; idx < 16 * DS; idx += 256) {
        int pp = idx / DS, si = idx % DS;
        int n = b * NN + n0 + pp;
        bmout[(size_t)n * DS + si] = bc[pp][si];
        cmout[(size_t)n * DS + si] = bc[pp][DS + si];
    }

    // dt_proj + softplus: lane=(p,q): d = q*48 + w*12 + jd
    float dv[12];
    {
        int d0 = q * 48 + w * 12;
        #pragma unroll
        for (int jd = 0; jd < 12; ++jd) {
            int d = d0 + jd;
            float v = dpb[d];
            #pragma unroll
            for (int r = 0; r < DTRK; ++r) v = fmaf(dpw[d * DTRK + r], dtrT[r][p], v);
            v = (v > 20.f) ? v : log1pf(expf(v));
            dv[jd] = v;
        }
    }
    __syncthreads();   // xcv reads all done; safe to overwrite
    {
        int d0 = q * 48 + w * 12;
        #pragma unroll
        for (int jd = 0; jd < 12; ++jd) xcv[p][d0 + jd] = dv[jd];
    }
    __syncthreads();
    for (int idx = t; idx < 16 * 48; idx += 256) {
        int pp = idx / 48, o4 = idx % 48;
        *(float4*)&dtout[((size_t)b * NN + n0 + pp) * DI + o4 * 4] = *(const float4*)&xcv[pp][o4 * 4];
    }
}

// ---------------- E: scan phase 1 — per-chunk (prod A, local B), LDS-staged ----------------
__launch_bounds__(256)
__global__ void k_scan1(const float* __restrict__ aexp, const float* __restrict__ dt,
                        const float* __restrict__ xcv, const float* __restrict__ bm,
                        float* __restrict__ ca, float* __restrict__ cbv) {
    __shared__ float dt_t[64][16], xcv_t[64][16], bm_t[64][16];
    int t = threadIdx.x;
    int kc = blockIdx.x, dblk = blockIdx.y, b = blockIdx.z;
    size_t nbase = (size_t)b * NN + kc * LCH;
    for (int idx = t; idx < 1024; idx += 256) {
        int i = idx >> 4, v = idx & 15;
        dt_t[i][v]  = dt [(nbase + i) * DI + dblk * 16 + v];
        xcv_t[i][v] = xcv[(nbase + i) * DI + dblk * 16 + v];
        bm_t[i][v]  = bm [(nbase + i) * DS + v];
    }
    __syncthreads();
    int s = t & 15, dl = t >> 4;
    float a = aexp[(dblk * 16 + dl) * DS + s];
    float ap = 1.f, bv = 0.f;
    #pragma unroll 8
    for (int i = 0; i < LCH; ++i) {
        float dtv = dt_t[i][dl];
        float dA = __expf(dtv * a);
        ap *= dA;
        bv = fmaf(dA, bv, dtv * bm_t[i][s] * xcv_t[i][dl]);
    }
    size_t cidx = ((size_t)(b * KCH + kc)) * (DI * DS) + dblk * 256 + t;
    ca[cidx] = ap;
    cbv[cidx] = bv;
}

// ---------------- F: scan phase 2 — sequential over chunks ----------------
__global__ void k_scan2(const float* __restrict__ ca, const float* __restrict__ cbv,
                        float* __restrict__ hs) {
    int tid = blockIdx.x * 64 + threadIdx.x; // 6144 total
    int b = tid / (DI * DS), dsx = tid % (DI * DS);
    float h = 0.f;
    size_t base = (size_t)b * KCH * (DI * DS) + dsx;
    #pragma unroll 5
    for (int kc = 0; kc < KCH; ++kc) {
        size_t idx = base + (size_t)kc * (DI * DS);
        hs[idx] = h;
        h = fmaf(ca[idx], h, cbv[idx]);
    }
}

// ---------------- G: scan phase 3 — replay + y + gate, LDS-staged ----------------
__launch_bounds__(256)
__global__ void k_scan3(const float* __restrict__ aexp, const float* __restrict__ Dp,
                        const float* __restrict__ dt, const float* __restrict__ xcv,
                        const float* __restrict__ bm, const float* __restrict__ cm,
                        const float* __restrict__ zin, const float* __restrict__ hs,
                        float* __restrict__ yout) {
    __shared__ float dt_t[64][16], xcv_t[64][16], bm_t[64][16], cm_t[64][16], z_t[64][16], y_t[64][16];
    int t = threadIdx.x;
    int kc = blockIdx.x, dblk = blockIdx.y, b = blockIdx.z;
    size_t nbase = (size_t)b * NN + kc * LCH;
    for (int idx = t; idx < 1024; idx += 256) {
        int i = idx >> 4, v = idx & 15;
        dt_t[i][v]  = dt [(nbase + i) * DI + dblk * 16 + v];
        xcv_t[i][v] = xcv[(nbase + i) * DI + dblk * 16 + v];
        z_t[i][v]   = zin[(nbase + i) * DI + dblk * 16 + v];
        bm_t[i][v]  = bm [(nbase + i) * DS + v];
        cm_t[i][v]  = cm [(nbase + i) * DS + v];
    }
    __syncthreads();
    int s = t & 15, dl = t >> 4;
    int d = dblk * 16 + dl;
    float a = aexp[d * DS + s];
    float dpar = Dp[d];
    float h = hs[((size_t)(b * KCH + kc)) * (DI * DS) + dblk * 256 + t];
    for (int i = 0; i < LCH; ++i) {
        float dtv = dt_t[i][dl];
        float xv  = xcv_t[i][dl];
        float dA = __expf(dtv * a);
        h = fmaf(dA, h, dtv * bm_t[i][s] * xv);
        float r = h * cm_t[i][s];
        r += __shfl_xor(r, 1);
        r += __shfl_xor(r, 2);
        r += __shfl_xor(r, 4);
        r += __shfl_xor(r, 8);
        if (s == 0) {
            float y = r + dpar * xv;
            float zv = z_t[i][dl];
            y *= zv / (1.f + expf(-zv));
            y_t[i][dl] = y;
        }
    }
    __syncthreads();
    for (int idx = t; idx < 1024; idx += 256) {
        int i = idx >> 4, v = idx & 15;
        yout[(nbase + i) * DI + dblk * 16 + v] = y_t[i][v];
    }
}

// ------- H: out_proj (192 -> 96), 16-pos tiles, 4-way K-split -------
__launch_bounds__(256, 4)
__global__ void k_outproj(const float* __restrict__ ow, const float* __restrict__ yin,
                          float* __restrict__ yp) {
    __shared__ float yt[16][196];
    __shared__ float yo[16][100];
    int b = blockIdx.y, n0 = blockIdx.x * 16, t = threadIdx.x;
    int lane = t & 63, w = t >> 6;
    int p = lane & 15, q = lane >> 4;
    for (int idx = t; idx < 16 * 48; idx += 256) {
        int pp = idx / 48, c4 = idx % 48;
        *(float4*)&yt[pp][c4 * 4] = *(const float4*)&yin[((size_t)b * NN + n0 + pp) * DI + c4 * 4];
    }
    __syncthreads();
    float acc[24];
    #pragma unroll
    for (int j = 0; j < 24; ++j) acc[j] = 0.f;
    for (int ci = 0; ci < 12; ++ci) {
        int c4 = q * 12 + ci;
        float4 yv = *(const float4*)&yt[p][c4 * 4];
        #pragma unroll
        for (int j = 0; j < 24; ++j) {
            int og = w + 4 * j;
            float4 w4 = *(const float4*)&ow[(size_t)og * DI + c4 * 4];
            acc[j] = fmaf(yv.x, w4.x, fmaf(yv.y, w4.y, fmaf(yv.z, w4.z, fmaf(yv.w, w4.w, acc[j]))));
        }
    }
    #pragma unroll
    for (int j = 0; j < 24; ++j) {
        acc[j] += __shfl_xor(acc[j], 16);
        acc[j] += __shfl_xor(acc[j], 32);
    }
    if (lane < 16) {
        #pragma unroll
        for (int j = 0; j < 24; ++j) yo[p][w + 4 * j] = acc[j];
    }
    __syncthreads();
    for (int idx = t; idx < 16 * 24; idx += 256) {
        int pp = idx / 24, o4 = idx % 24;
        *(float4*)&yp[((size_t)b * NN + n0 + pp) * NC + o4 * 4] = *(const float4*)&yo[pp][o4 * 4];
    }
}

// ---------------- I: gather rows by rank + transpose + coalesced final write ----------------
__launch_bounds__(256)
__global__ void k_final(const float* __restrict__ yp, const int* __restrict__ rank,
                        float* __restrict__ out) {
    __shared__ float ft[64][97];
    __shared__ int rk[64];
    int b = blockIdx.y, i0 = blockIdx.x * 64, t = threadIdx.x;
    if (t < 64) rk[t] = rank[i0 + t];
    __syncthreads();
    for (int idx = t; idx < 64 * 24; idx += 256) {
        int ii = idx / 24, j = idx % 24;
        float4 v = *(const float4*)&yp[((size_t)b * NN + rk[ii]) * NC + j * 4];
        ft[ii][j * 4 + 0] = v.x; ft[ii][j * 4 + 1] = v.y;
        ft[ii][j * 4 + 2] = v.z; ft[ii][j * 4 + 3] = v.w;
    }
    __syncthreads();
    for (int idx = t; idx < 96 * 64; idx += 256) {
        int c = idx >> 6, ii = idx & 63;
        out[((size_t)b * NC + c) * NN + i0 + ii] = ft[ii][c];
    }
}

extern "C" void kernel_launch(void* const* d_in, const int* in_sizes, int n_in,
                              void* d_out, int out_size, void* d_ws, size_t ws_size,
                              hipStream_t stream) {
    const float* x    = (const float*)d_in[0];
    const float* pv   = (const float*)d_in[1];
    const float* nw   = (const float*)d_in[2];
    const float* nbp  = (const float*)d_in[3];
    const float* win  = (const float*)d_in[4];
    const float* cw   = (const float*)d_in[5];
    const float* cb   = (const float*)d_in[6];
    const float* xpw  = (const float*)d_in[7];
    const float* dpw  = (const float*)d_in[8];
    const float* dpb  = (const float*)d_in[9];
    const float* alog = (const float*)d_in[10];
    const float* Dp   = (const float*)d_in[11];
    const float* ow   = (const float*)d_in[12];
    float* out = (float*)d_out;
    float* ws  = (float*)d_ws;

    float* keys = ws + OFF_KEYS;
    int*   rank = (int*)ws + OFF_RANK;
    float* aexp = ws + OFF_AEXP;
    float* xc   = ws + OFF_XC;
    float* z    = ws + OFF_Z;
    float* xcv  = ws + OFF_XCV;
    float* dt   = ws + OFF_DT;
    float* bmb  = ws + OFF_BM;
    float* cmb  = ws + OFF_CM;
    float* ca   = ws + OFF_CA;
    float* cbv  = ws + OFF_CB;
    float* hs   = ws + OFF_HS;
    float* xn   = ws + OFF_CA;  // alias: ca/cbv not yet live (scan1 runs later)
    float* y    = ws + OFF_XC;  // alias: xc dead after conv stage
    float* yp   = ws + OFF_DT;  // alias: dt dead after scan3

    hipMemsetAsync(rank, 0, NN * sizeof(int), stream);
    k_keys<<<(NN + DI * DS + 255) / 256, 256, 0, stream>>>(pv, alog, keys, aexp);
    k_rank<<<dim3(32, 32), 256, 0, stream>>>(keys, rank);
    k_ln<<<dim3(125, 2), 256, 0, stream>>>(x, nw, nbp, rank, xn);
    k_inproj<<<dim3(125, 4, 2), 256, 0, stream>>>(xn, win, xc, z);
    k_conv_xdt<<<dim3(500, 2), 256, 0, stream>>>(cw, cb, xpw, dpw, dpb, xc, xcv, dt, bmb, cmb);
    k_scan1<<<dim3(KCH, 12, NB), 256, 0, stream>>>(aexp, dt, xcv, bmb, ca, cbv);
    k_scan2<<<96, 64, 0, stream>>>(ca, cbv, hs);
    k_scan3<<<dim3(KCH, 12, NB), 256, 0, stream>>>(aexp, Dp, dt, xcv, bmb, cmb, z, hs, y);
    k_outproj<<<dim3(500, 2), 256, 0, stream>>>(ow, y, yp);
    k_final<<<dim3(125, 2), 256, 0, stream>>>(yp, rank, out);
}

// Round 6
// 239.765 us; speedup vs baseline: 1.9639x; 1.2170x over previous
//
#include <hip/hip_runtime.h>
#include <math.h>

#define NB 2
#define NC 96
#define NN 8000
#define DI 192
#define DS 16
#define DTRK 6
#define KCH 125
#define LCH 64

// ws layout (element offsets, 4B each)
#define OFF_KEYS 0
#define OFF_RANK 8000
#define OFF_AEXP 24000
#define OFF_XC   32768                        // (B,N,DI) — reused as Y after scan
#define OFF_Z    (OFF_XC  + NB*NN*DI)
#define OFF_XCV  (OFF_Z   + NB*NN*DI)
#define OFF_DT   (OFF_XCV + NB*NN*DI)         // reused as YP (B,N,96) after scan3
#define OFF_BM   (OFF_DT  + NB*NN*DI)
#define OFF_CM   (OFF_BM  + NB*NN*DS)
#define OFF_CA   (OFF_CM  + NB*NN*DS)         // xn (B,N,96) aliases ca+cb (pre-scan)
#define OFF_CB   (OFF_CA  + NB*KCH*DI*DS)
#define OFF_HS   (OFF_CB  + NB*KCH*DI*DS)

// ---------------- A1: projection keys + A = -exp(A_log) ----------------
__global__ void k_keys(const float* __restrict__ pv, const float* __restrict__ alog,
                       float* __restrict__ keys, float* __restrict__ aexp) {
    int t = blockIdx.x * 256 + threadIdx.x;
    if (t < NN) {
        int z = t / 400, rem = t % 400, y = rem / 20, x = rem % 20;
        keys[t] = (float)z * pv[0] + (float)y * pv[1] + (float)x * pv[2];
    } else if (t < NN + DI * DS) {
        int i = t - NN;
        aexp[i] = -expf(alog[i]);
    }
}

// ---------------- A2: O(N^2) stable rank (tie-break on index) ----------------
__global__ void k_rank(const float* __restrict__ keys, int* __restrict__ rank) {
    __shared__ float kj[250];
    int t = threadIdx.x;
    int j0 = blockIdx.y * 250;
    if (t < 250) kj[t] = keys[j0 + t];
    __syncthreads();
    int i = blockIdx.x * 256 + t;
    if (i >= NN) return;
    float ki = keys[i];
    int cnt = 0;
    #pragma unroll 5
    for (int j = 0; j < 250; ++j) {
        float kv = kj[j];
        int jj = j0 + j;
        cnt += (kv < ki || (kv == ki && jj < i)) ? 1 : 0;
    }
    atomicAdd(rank + i, cnt);
}

// ------- B1: LayerNorm + row-scatter to sorted xn (B,N,96) -------
__launch_bounds__(256)
__global__ void k_ln(const float* __restrict__ x, const float* __restrict__ nw,
                     const float* __restrict__ nbp, const int* __restrict__ rank,
                     float* __restrict__ xn) {
    __shared__ float xt[64][100];
    __shared__ int rk[64];
    __shared__ float nwb[NC], nbb[NC];
    int b = blockIdx.y, n0 = blockIdx.x * 64, t = threadIdx.x;
    int lane = t & 63, w = t >> 6;
    if (t < 64) rk[t] = rank[n0 + t];
    else if (t < 160) { int c = t - 64; nwb[c] = nw[c]; nbb[c] = nbp[c]; }
    for (int idx = t; idx < NC * 64; idx += 256) {
        int c = idx >> 6, p = idx & 63;
        xt[p][c] = x[((size_t)b * NC + c) * NN + n0 + p];
    }
    __syncthreads();
    // per-lane LN (4 waves redundant)
    float xr[96];
    float s = 0.f, sq = 0.f;
    #pragma unroll
    for (int c4 = 0; c4 < 24; ++c4) {
        float4 v = *(const float4*)&xt[lane][c4 * 4];
        xr[c4*4+0] = v.x; xr[c4*4+1] = v.y; xr[c4*4+2] = v.z; xr[c4*4+3] = v.w;
        s += v.x + v.y + v.z + v.w;
        sq += v.x*v.x + v.y*v.y + v.z*v.z + v.w*v.w;
    }
    float mu = s * (1.f / 96.f);
    float var = sq * (1.f / 96.f) - mu * mu;
    float rs = rsqrtf(var + 1e-5f);
    #pragma unroll
    for (int c = 0; c < 96; ++c) xr[c] = (xr[c] - mu) * rs * nwb[c] + nbb[c];
    __syncthreads();
    if (w == 0) {
        #pragma unroll
        for (int c = 0; c < 96; ++c) xt[lane][c] = xr[c];
    }
    __syncthreads();
    for (int idx = t; idx < 64 * 24; idx += 256) {
        int p = idx / 24, c4 = idx % 24;
        *(float4*)&xn[((size_t)b * NN + rk[p]) * NC + c4 * 4] = *(const float4*)&xt[p][c4 * 4];
    }
}

// ------- B2: in_proj GEMM, W-tile staged in LDS, uniform broadcast reads -------
__launch_bounds__(256, 2)
__global__ void k_inproj(const float* __restrict__ xn, const float* __restrict__ win,
                         float* __restrict__ xcout, float* __restrict__ zout) {
    __shared__ float wsm[96 * 96];             // 36.9 KB: W rows [g*96, g*96+96)
    __shared__ float smem[64 * 104];           // union: xs[96][65] then st[64][104]
    float (*xs)[65]  = (float(*)[65])smem;
    float (*st)[104] = (float(*)[104])smem;
    int b = blockIdx.z, g = blockIdx.y, n0 = blockIdx.x * 64, t = threadIdx.x;
    int lane = t & 63, w = t >> 6;

    const float4* wsrc = (const float4*)(win + (size_t)g * 96 * NC);
    for (int i = t; i < 96 * 96 / 4; i += 256) ((float4*)wsm)[i] = wsrc[i];
    for (int idx = t; idx < 64 * 96; idx += 256) {
        int p = idx / 96, c = idx % 96;
        xs[c][p] = xn[((size_t)b * NN + n0 + p) * NC + c];
    }
    __syncthreads();

    float acc[24];
    #pragma unroll
    for (int j = 0; j < 24; ++j) acc[j] = 0.f;
    const float* wrow = wsm + w * 24 * 96;
    for (int c4 = 0; c4 < 24; ++c4) {
        float x0 = xs[c4*4+0][lane], x1 = xs[c4*4+1][lane];
        float x2 = xs[c4*4+2][lane], x3 = xs[c4*4+3][lane];
        #pragma unroll
        for (int j = 0; j < 24; ++j) {
            float4 w4 = *(const float4*)(wrow + j * 96 + c4 * 4);
            acc[j] = fmaf(x0, w4.x, fmaf(x1, w4.y, fmaf(x2, w4.z, fmaf(x3, w4.w, acc[j]))));
        }
    }
    __syncthreads();   // xs dead
    #pragma unroll
    for (int j = 0; j < 24; ++j) st[lane][w * 24 + j] = acc[j];
    __syncthreads();
    float* outp = (g < 2) ? xcout : zout;
    int co = (g & 1) * 96;
    for (int idx = t; idx < 64 * 24; idx += 256) {
        int p = idx / 24, o4 = idx % 24;
        *(float4*)&outp[((size_t)b * NN + n0 + p) * DI + co + o4 * 4] = *(const float4*)&st[p][o4 * 4];
    }
}

// ------- D: conv+silu + x_proj + dt_proj, 16-pos tiles, 4-way K-split -------
__launch_bounds__(256, 4)
__global__ void k_conv_xdt(const float* __restrict__ cw, const float* __restrict__ cb,
                           const float* __restrict__ xpw, const float* __restrict__ dpw,
                           const float* __restrict__ dpb, const float* __restrict__ xcin,
                           float* __restrict__ xcvout, float* __restrict__ dtout,
                           float* __restrict__ bmout, float* __restrict__ cmout) {
    __shared__ float xcv[16][196];             // reused as dt stage at the end
    __shared__ float dtrT[DTRK][16];
    __shared__ float bc[16][33];
    int b = blockIdx.y, n0 = blockIdx.x * 16, t = threadIdx.x;
    int lane = t & 63, w = t >> 6;
    int p = lane & 15, q = lane >> 4;

    // conv + silu
    for (int idx = t; idx < 16 * DI; idx += 256) {
        int pp = idx / DI, d = idx % DI;
        float s = cb[d];
        #pragma unroll
        for (int k = 0; k < 4; ++k) {
            int n = n0 + pp - 3 + k;
            float xv = (n >= 0) ? xcin[((size_t)b * NN + n) * DI + d] : 0.f;
            s = fmaf(cw[d * 4 + k], xv, s);
        }
        s = s / (1.f + expf(-s));
        xcv[pp][d] = s;
        xcvout[((size_t)b * NN + n0 + pp) * DI + d] = s;
    }
    __syncthreads();

    // x_proj: lane=(p,q); q = K-quarter; wave w -> outputs e = w+4j
    float acc[10];
    #pragma unroll
    for (int j = 0; j < 10; ++j) acc[j] = 0.f;
    for (int ci = 0; ci < 12; ++ci) {
        int c4 = q * 12 + ci;
        float4 xv = *(const float4*)&xcv[p][c4 * 4];
        #pragma unroll
        for (int j = 0; j < 10; ++j) {
            int e = w + 4 * j;
            if (e < 38) {
                float4 w4 = *(const float4*)&xpw[(size_t)e * DI + c4 * 4];
                acc[j] = fmaf(xv.x, w4.x, fmaf(xv.y, w4.y, fmaf(xv.z, w4.z, fmaf(xv.w, w4.w, acc[j]))));
            }
        }
    }
    #pragma unroll
    for (int j = 0; j < 10; ++j) {
        acc[j] += __shfl_xor(acc[j], 16);
        acc[j] += __shfl_xor(acc[j], 32);
    }
    if (lane < 16) {
        #pragma unroll
        for (int j = 0; j < 10; ++j) {
            int e = w + 4 * j;
            if (e < DTRK) dtrT[e][p] = acc[j];
            else if (e < 38) bc[p][e - DTRK] = acc[j];
        }
    }
    __syncthreads();

    // Bm/Cm coalesced
    for (int idx = t; idx < 16 * DS; idx += 256) {
        int pp = idx / DS, si = idx % DS;
        int n = b * NN + n0 + pp;
        bmout[(size_t)n * DS + si] = bc[pp][si];
        cmout[(size_t)n * DS + si] = bc[pp][DS + si];
    }

    // dt_proj + softplus: lane=(p,q): d = q*48 + w*12 + jd
    float dv[12];
    {
        int d0 = q * 48 + w * 12;
        #pragma unroll
        for (int jd = 0; jd < 12; ++jd) {
            int d = d0 + jd;
            float v = dpb[d];
            #pragma unroll
            for (int r = 0; r < DTRK; ++r) v = fmaf(dpw[d * DTRK + r], dtrT[r][p], v);
            v = (v > 20.f) ? v : log1pf(expf(v));
            dv[jd] = v;
        }
    }
    __syncthreads();   // xcv reads all done; safe to overwrite
    {
        int d0 = q * 48 + w * 12;
        #pragma unroll
        for (int jd = 0; jd < 12; ++jd) xcv[p][d0 + jd] = dv[jd];
    }
    __syncthreads();
    for (int idx = t; idx < 16 * 48; idx += 256) {
        int pp = idx / 48, o4 = idx % 48;
        *(float4*)&dtout[((size_t)b * NN + n0 + pp) * DI + o4 * 4] = *(const float4*)&xcv[pp][o4 * 4];
    }
}

// ---------------- E: scan phase 1 — per-chunk (prod A, local B), LDS-staged ----------------
__launch_bounds__(256)
__global__ void k_scan1(const float* __restrict__ aexp, const float* __restrict__ dt,
                        const float* __restrict__ xcv, const float* __restrict__ bm,
                        float* __restrict__ ca, float* __restrict__ cbv) {
    __shared__ float dt_t[64][16], xcv_t[64][16], bm_t[64][16];
    int t = threadIdx.x;
    int kc = blockIdx.x, dblk = blockIdx.y, b = blockIdx.z;
    size_t nbase = (size_t)b * NN + kc * LCH;
    for (int idx = t; idx < 1024; idx += 256) {
        int i = idx >> 4, v = idx & 15;
        dt_t[i][v]  = dt [(nbase + i) * DI + dblk * 16 + v];
        xcv_t[i][v] = xcv[(nbase + i) * DI + dblk * 16 + v];
        bm_t[i][v]  = bm [(nbase + i) * DS + v];
    }
    __syncthreads();
    int s = t & 15, dl = t >> 4;
    float a = aexp[(dblk * 16 + dl) * DS + s];
    float ap = 1.f, bv = 0.f;
    #pragma unroll 8
    for (int i = 0; i < LCH; ++i) {
        float dtv = dt_t[i][dl];
        float dA = __expf(dtv * a);
        ap *= dA;
        bv = fmaf(dA, bv, dtv * bm_t[i][s] * xcv_t[i][dl]);
    }
    size_t cidx = ((size_t)(b * KCH + kc)) * (DI * DS) + dblk * 256 + t;
    ca[cidx] = ap;
    cbv[cidx] = bv;
}

// ---------------- F: scan phase 2 — sequential over chunks ----------------
__global__ void k_scan2(const float* __restrict__ ca, const float* __restrict__ cbv,
                        float* __restrict__ hs) {
    int tid = blockIdx.x * 64 + threadIdx.x; // 6144 total
    int b = tid / (DI * DS), dsx = tid % (DI * DS);
    float h = 0.f;
    size_t base = (size_t)b * KCH * (DI * DS) + dsx;
    #pragma unroll 5
    for (int kc = 0; kc < KCH; ++kc) {
        size_t idx = base + (size_t)kc * (DI * DS);
        hs[idx] = h;
        h = fmaf(ca[idx], h, cbv[idx]);
    }
}

// ---------------- G: scan phase 3 — replay + y + gate, LDS-staged ----------------
__launch_bounds__(256)
__global__ void k_scan3(const float* __restrict__ aexp, const float* __restrict__ Dp,
                        const float* __restrict__ dt, const float* __restrict__ xcv,
                        const float* __restrict__ bm, const float* __restrict__ cm,
                        const float* __restrict__ zin, const float* __restrict__ hs,
                        float* __restrict__ yout) {
    __shared__ float dt_t[64][16], xcv_t[64][16], bm_t[64][16], cm_t[64][16], z_t[64][16], y_t[64][16];
    int t = threadIdx.x;
    int kc = blockIdx.x, dblk = blockIdx.y, b = blockIdx.z;
    size_t nbase = (size_t)b * NN + kc * LCH;
    for (int idx = t; idx < 1024; idx += 256) {
        int i = idx >> 4, v = idx & 15;
        dt_t[i][v]  = dt [(nbase + i) * DI + dblk * 16 + v];
        xcv_t[i][v] = xcv[(nbase + i) * DI + dblk * 16 + v];
        z_t[i][v]   = zin[(nbase + i) * DI + dblk * 16 + v];
        bm_t[i][v]  = bm [(nbase + i) * DS + v];
        cm_t[i][v]  = cm [(nbase + i) * DS + v];
    }
    __syncthreads();
    int s = t & 15, dl = t >> 4;
    int d = dblk * 16 + dl;
    float a = aexp[d * DS + s];
    float dpar = Dp[d];
    float h = hs[((size_t)(b * KCH + kc)) * (DI * DS) + dblk * 256 + t];
    for (int i = 0; i < LCH; ++i) {
        float dtv = dt_t[i][dl];
        float xv  = xcv_t[i][dl];
        float dA = __expf(dtv * a);
        h = fmaf(dA, h, dtv * bm_t[i][s] * xv);
        float r = h * cm_t[i][s];
        r += __shfl_xor(r, 1);
        r += __shfl_xor(r, 2);
        r += __shfl_xor(r, 4);
        r += __shfl_xor(r, 8);
        if (s == 0) {
            float y = r + dpar * xv;
            float zv = z_t[i][dl];
            y *= zv / (1.f + expf(-zv));
            y_t[i][dl] = y;
        }
    }
    __syncthreads();
    for (int idx = t; idx < 1024; idx += 256) {
        int i = idx >> 4, v = idx & 15;
        yout[(nbase + i) * DI + dblk * 16 + v] = y_t[i][v];
    }
}

// ------- H: out_proj (192 -> 96), W-tile in LDS, lane=position -------
__launch_bounds__(256, 2)
__global__ void k_outproj(const float* __restrict__ ow, const float* __restrict__ yin,
                          float* __restrict__ yp) {
    __shared__ float wsm[32 * 192];            // 24.6 KB: W rows [g*32, g*32+32)
    __shared__ float yt[64][193];              // 49.4 KB
    float (*yo)[40] = (float(*)[40])wsm;       // union after GEMM (10.2 KB)
    int b = blockIdx.z, g = blockIdx.y, n0 = blockIdx.x * 64, t = threadIdx.x;
    int lane = t & 63, w = t >> 6;

    const float4* wsrc = (const float4*)(ow + (size_t)g * 32 * DI);
    for (int i = t; i < 32 * 192 / 4; i += 256) ((float4*)wsm)[i] = wsrc[i];
    for (int idx = t; idx < 64 * 48; idx += 256) {
        int p = idx / 48, c4 = idx % 48;
        float4 v = *(const float4*)&yin[((size_t)b * NN + n0 + p) * DI + c4 * 4];
        yt[p][c4*4+0] = v.x; yt[p][c4*4+1] = v.y;
        yt[p][c4*4+2] = v.z; yt[p][c4*4+3] = v.w;
    }
    __syncthreads();

    float acc[8];
    #pragma unroll
    for (int j = 0; j < 8; ++j) acc[j] = 0.f;
    const float* wrow = wsm + w * 8 * 192;
    for (int c4 = 0; c4 < 48; ++c4) {
        float y0 = yt[lane][c4*4+0], y1 = yt[lane][c4*4+1];
        float y2 = yt[lane][c4*4+2], y3 = yt[lane][c4*4+3];
        #pragma unroll
        for (int j = 0; j < 8; ++j) {
            float4 w4 = *(const float4*)(wrow + j * 192 + c4 * 4);
            acc[j] = fmaf(y0, w4.x, fmaf(y1, w4.y, fmaf(y2, w4.z, fmaf(y3, w4.w, acc[j]))));
        }
    }
    __syncthreads();   // wsm dead -> yo
    #pragma unroll
    for (int j = 0; j < 8; ++j) yo[lane][w * 8 + j] = acc[j];
    __syncthreads();
    for (int idx = t; idx < 64 * 8; idx += 256) {
        int p = idx / 8, o4 = idx % 8;
        *(float4*)&yp[((size_t)b * NN + n0 + p) * NC + g * 32 + o4 * 4] = *(const float4*)&yo[p][o4 * 4];
    }
}

// ---------------- I: gather rows by rank + transpose + coalesced final write ----------------
__launch_bounds__(256)
__global__ void k_final(const float* __restrict__ yp, const int* __restrict__ rank,
                        float* __restrict__ out) {
    __shared__ float ft[64][97];
    __shared__ int rk[64];
    int b = blockIdx.y, i0 = blockIdx.x * 64, t = threadIdx.x;
    if (t < 64) rk[t] = rank[i0 + t];
    __syncthreads();
    for (int idx = t; idx < 64 * 24; idx += 256) {
        int ii = idx / 24, j = idx % 24;
        float4 v = *(const float4*)&yp[((size_t)b * NN + rk[ii]) * NC + j * 4];
        ft[ii][j * 4 + 0] = v.x; ft[ii][j * 4 + 1] = v.y;
        ft[ii][j * 4 + 2] = v.z; ft[ii][j * 4 + 3] = v.w;
    }
    __syncthreads();
    for (int idx = t; idx < 96 * 64; idx += 256) {
        int c = idx >> 6, ii = idx & 63;
        out[((size_t)b * NC + c) * NN + i0 + ii] = ft[ii][c];
    }
}

extern "C" void kernel_launch(void* const* d_in, const int* in_sizes, int n_in,
                              void* d_out, int out_size, void* d_ws, size_t ws_size,
                              hipStream_t stream) {
    const float* x    = (const float*)d_in[0];
    const float* pv   = (const float*)d_in[1];
    const float* nw   = (const float*)d_in[2];
    const float* nbp  = (const float*)d_in[3];
    const float* win  = (const float*)d_in[4];
    const float* cw   = (const float*)d_in[5];
    const float* cb   = (const float*)d_in[6];
    const float* xpw  = (const float*)d_in[7];
    const float* dpw  = (const float*)d_in[8];
    const float* dpb  = (const float*)d_in[9];
    const float* alog = (const float*)d_in[10];
    const float* Dp   = (const float*)d_in[11];
    const float* ow   = (const float*)d_in[12];
    float* out = (float*)d_out;
    float* ws  = (float*)d_ws;

    float* keys = ws + OFF_KEYS;
    int*   rank = (int*)ws + OFF_RANK;
    float* aexp = ws + OFF_AEXP;
    float* xc   = ws + OFF_XC;
    float* z    = ws + OFF_Z;
    float* xcv  = ws + OFF_XCV;
    float* dt   = ws + OFF_DT;
    float* bmb  = ws + OFF_BM;
    float* cmb  = ws + OFF_CM;
    float* ca   = ws + OFF_CA;
    float* cbv  = ws + OFF_CB;
    float* hs   = ws + OFF_HS;
    float* xn   = ws + OFF_CA;  // alias: ca/cbv not yet live (scan1 runs later)
    float* y    = ws + OFF_XC;  // alias: xc dead after conv stage
    float* yp   = ws + OFF_DT;  // alias: dt dead after scan3

    hipMemsetAsync(rank, 0, NN * sizeof(int), stream);
    k_keys<<<(NN + DI * DS + 255) / 256, 256, 0, stream>>>(pv, alog, keys, aexp);
    k_rank<<<dim3(32, 32), 256, 0, stream>>>(keys, rank);
    k_ln<<<dim3(125, 2), 256, 0, stream>>>(x, nw, nbp, rank, xn);
    k_inproj<<<dim3(125, 4, 2), 256, 0, stream>>>(xn, win, xc, z);
    k_conv_xdt<<<dim3(500, 2), 256, 0, stream>>>(cw, cb, xpw, dpw, dpb, xc, xcv, dt, bmb, cmb);
    k_scan1<<<dim3(KCH, 12, NB), 256, 0, stream>>>(aexp, dt, xcv, bmb, ca, cbv);
    k_scan2<<<96, 64, 0, stream>>>(ca, cbv, hs);
    k_scan3<<<dim3(KCH, 12, NB), 256, 0, stream>>>(aexp, Dp, dt, xcv, bmb, cmb, z, hs, y);
    k_outproj<<<dim3(125, 3, 2), 256, 0, stream>>>(ow, y, yp);
    k_final<<<dim3(125, 2), 256, 0, stream>>>(yp, rank, out);
}